// Round 3
// baseline (135.887 us; speedup 1.0000x reference)
//
#include <hip/hip_runtime.h>
#include <math.h>

#define N_ 4096
#define M_ 4096
#define D_ 8
#define TINY_F 1.17549435e-38f

// Numerically stable softplus: log(1+exp(v)) = max(v,0) + log1p(exp(-|v|))
__device__ __forceinline__ float softplus_stable(float v) {
    return fmaxf(v, 0.0f) + log1pf(expf(-fabsf(v)));
}

__global__ __launch_bounds__(256) void rbf_kernel(
    const float* __restrict__ x,      // (N, D)
    const float* __restrict__ x2,     // (M, D)
    const float* __restrict__ ramp,   // (1,)
    const float* __restrict__ rls,    // (D,)
    float* __restrict__ out)          // (N, M)
{
    // Per-block parameter computation (9 softplus total, trivial cost).
    __shared__ float s_par[D_ + 1];   // [0..7] = 0.5/ls[d]^2, [8] = amp^2
    if (threadIdx.x < D_) {
        float l = softplus_stable(rls[threadIdx.x]) + TINY_F;
        s_par[threadIdx.x] = 0.5f / (l * l);
    } else if (threadIdx.x == D_) {
        float a = softplus_stable(ramp[0]) + TINY_F;
        s_par[D_] = a * a;
    }
    __syncthreads();

    const float c0 = s_par[0], c1 = s_par[1], c2 = s_par[2], c3 = s_par[3];
    const float c4 = s_par[4], c5 = s_par[5], c6 = s_par[6], c7 = s_par[7];
    const float amp2 = s_par[D_];

    const int i  = blockIdx.y;                                  // row of x
    const int j0 = (blockIdx.x * 256 + threadIdx.x) * 4;        // first col of x2

    // x row: uniform address across the block -> scalar-load path.
    const float4 xa = *reinterpret_cast<const float4*>(x + (size_t)i * D_);
    const float4 xb = *reinterpret_cast<const float4*>(x + (size_t)i * D_ + 4);

    float r[4];
#pragma unroll
    for (int jj = 0; jj < 4; ++jj) {
        const float4 a = *reinterpret_cast<const float4*>(x2 + (size_t)(j0 + jj) * D_);
        const float4 b = *reinterpret_cast<const float4*>(x2 + (size_t)(j0 + jj) * D_ + 4);
        float d0 = xa.x - a.x;
        float d1 = xa.y - a.y;
        float d2 = xa.z - a.z;
        float d3 = xa.w - a.w;
        float d4 = xb.x - b.x;
        float d5 = xb.y - b.y;
        float d6 = xb.z - b.z;
        float d7 = xb.w - b.w;
        float acc;
        acc = d0 * d0 * c0;
        acc = fmaf(d1 * d1, c1, acc);
        acc = fmaf(d2 * d2, c2, acc);
        acc = fmaf(d3 * d3, c3, acc);
        acc = fmaf(d4 * d4, c4, acc);
        acc = fmaf(d5 * d5, c5, acc);
        acc = fmaf(d6 * d6, c6, acc);
        acc = fmaf(d7 * d7, c7, acc);
        r[jj] = amp2 * __expf(-acc);
    }

    float4 res = make_float4(r[0], r[1], r[2], r[3]);
    *reinterpret_cast<float4*>(out + (size_t)i * M_ + j0) = res;
}

extern "C" void kernel_launch(void* const* d_in, const int* in_sizes, int n_in,
                              void* d_out, int out_size, void* d_ws, size_t ws_size,
                              hipStream_t stream) {
    const float* x    = (const float*)d_in[0];
    const float* x2   = (const float*)d_in[1];
    const float* ramp = (const float*)d_in[2];
    const float* rls  = (const float*)d_in[3];
    float* out = (float*)d_out;

    dim3 block(256);
    dim3 grid(M_ / (4 * 256), N_);   // (4, 4096)
    rbf_kernel<<<grid, block, 0, stream>>>(x, x2, ramp, rls, out);
}

// Round 5
// 90.820 us; speedup vs baseline: 1.4962x; 1.4962x over previous
//
#include <hip/hip_runtime.h>
#include <math.h>

#define N_ 4096
#define M_ 4096
#define D_ 8
#define TI 8                        // x-rows per block (amortizes x2 loads)
#define TINY_F 1.17549435e-38f

typedef float floatx4 __attribute__((ext_vector_type(4)));  // clang-native for nontemporal builtin

// Numerically stable softplus: log(1+exp(v)) = max(v,0) + log1p(exp(-|v|))
__device__ __forceinline__ float softplus_stable(float v) {
    return fmaxf(v, 0.0f) + log1pf(expf(-fabsf(v)));
}

__global__ __launch_bounds__(256) void rbf_kernel(
    const float* __restrict__ x,      // (N, D)
    const float* __restrict__ x2,     // (M, D)
    const float* __restrict__ ramp,   // (1,)
    const float* __restrict__ rls,    // (D,)
    float* __restrict__ out)          // (N, M)
{
    __shared__ float s_par[D_ + 1];   // [0..7] = 0.5/ls[d]^2, [8] = amp^2
    if (threadIdx.x < D_) {
        float l = softplus_stable(rls[threadIdx.x]) + TINY_F;
        s_par[threadIdx.x] = 0.5f / (l * l);
    } else if (threadIdx.x == D_) {
        float a = softplus_stable(ramp[0]) + TINY_F;
        s_par[D_] = a * a;
    }
    __syncthreads();

    const float c0 = s_par[0], c1 = s_par[1], c2 = s_par[2], c3 = s_par[3];
    const float c4 = s_par[4], c5 = s_par[5], c6 = s_par[6], c7 = s_par[7];
    const float amp2 = s_par[D_];

    const int t  = threadIdx.x;
    const int j0 = blockIdx.x * 1024 + t * 4;   // 4 consecutive x2 rows per thread
    const int i0 = blockIdx.y * TI;

    // Load this thread's 4 x2 rows ONCE (32 VGPRs), reuse across all TI x-rows.
    // (Strided pattern, but paid once per block instead of once per x-row.)
    float4 a[4], b[4];
#pragma unroll
    for (int jj = 0; jj < 4; ++jj) {
        a[jj] = *reinterpret_cast<const float4*>(x2 + (size_t)(j0 + jj) * D_);
        b[jj] = *reinterpret_cast<const float4*>(x2 + (size_t)(j0 + jj) * D_ + 4);
    }

#pragma unroll
    for (int ii = 0; ii < TI; ++ii) {
        const int i = i0 + ii;
        // Uniform address across block -> scalar-load path, L2-resident.
        const float4 xa = *reinterpret_cast<const float4*>(x + (size_t)i * D_);
        const float4 xb = *reinterpret_cast<const float4*>(x + (size_t)i * D_ + 4);

        float r[4];
#pragma unroll
        for (int jj = 0; jj < 4; ++jj) {
            float d0 = xa.x - a[jj].x;
            float d1 = xa.y - a[jj].y;
            float d2 = xa.z - a[jj].z;
            float d3 = xa.w - a[jj].w;
            float d4 = xb.x - b[jj].x;
            float d5 = xb.y - b[jj].y;
            float d6 = xb.z - b[jj].z;
            float d7 = xb.w - b[jj].w;
            float acc;
            acc = d0 * d0 * c0;
            acc = fmaf(d1 * d1, c1, acc);
            acc = fmaf(d2 * d2, c2, acc);
            acc = fmaf(d3 * d3, c3, acc);
            acc = fmaf(d4 * d4, c4, acc);
            acc = fmaf(d5 * d5, c5, acc);
            acc = fmaf(d6 * d6, c6, acc);
            acc = fmaf(d7 * d7, c7, acc);
            r[jj] = amp2 * __expf(-acc);
        }
        floatx4 res = { r[0], r[1], r[2], r[3] };
        // Streaming output (64 MiB > L2): nontemporal to avoid L2 thrash.
        __builtin_nontemporal_store(res,
            reinterpret_cast<floatx4*>(out + (size_t)i * M_ + j0));
    }
}

extern "C" void kernel_launch(void* const* d_in, const int* in_sizes, int n_in,
                              void* d_out, int out_size, void* d_ws, size_t ws_size,
                              hipStream_t stream) {
    const float* x    = (const float*)d_in[0];
    const float* x2   = (const float*)d_in[1];
    const float* ramp = (const float*)d_in[2];
    const float* rls  = (const float*)d_in[3];
    float* out = (float*)d_out;

    dim3 block(256);
    dim3 grid(M_ / 1024, N_ / TI);   // (4, 512) = 2048 blocks
    rbf_kernel<<<grid, block, 0, stream>>>(x, x2, ramp, rls, out);
}

// Round 8
// 89.298 us; speedup vs baseline: 1.5217x; 1.0170x over previous
//
#include <hip/hip_runtime.h>
#include <math.h>

#define N_ 4096
#define M_ 4096
#define D_ 8
#define TI 8                        // x-rows per block (amortizes x2 loads)
#define TINY_F 1.17549435e-38f

// Numerically stable softplus: log(1+exp(v)) = max(v,0) + log1p(exp(-|v|))
__device__ __forceinline__ float softplus_stable(float v) {
    return fmaxf(v, 0.0f) + log1pf(expf(-fabsf(v)));
}

__global__ __launch_bounds__(256) void rbf_kernel(
    const float* __restrict__ x,      // (N, D)
    const float* __restrict__ x2,     // (M, D)
    const float* __restrict__ ramp,   // (1,)
    const float* __restrict__ rls,    // (D,)
    float* __restrict__ out)          // (N, M)
{
    __shared__ float s_par[D_ + 1];   // [0..7] = 0.5/ls[d]^2, [8] = amp^2
    if (threadIdx.x < D_) {
        float l = softplus_stable(rls[threadIdx.x]) + TINY_F;
        s_par[threadIdx.x] = 0.5f / (l * l);
    } else if (threadIdx.x == D_) {
        float a = softplus_stable(ramp[0]) + TINY_F;
        s_par[D_] = a * a;
    }
    __syncthreads();

    const float c0 = s_par[0], c1 = s_par[1], c2 = s_par[2], c3 = s_par[3];
    const float c4 = s_par[4], c5 = s_par[5], c6 = s_par[6], c7 = s_par[7];
    const float amp2 = s_par[D_];

    const int t  = threadIdx.x;
    const int j0 = blockIdx.x * 1024 + t * 4;   // 4 consecutive x2 rows per thread
    const int i0 = blockIdx.y * TI;

    // Load this thread's 4 x2 rows ONCE (32 VGPRs), reuse across all TI x-rows.
    float4 a[4], b[4];
#pragma unroll
    for (int jj = 0; jj < 4; ++jj) {
        a[jj] = *reinterpret_cast<const float4*>(x2 + (size_t)(j0 + jj) * D_);
        b[jj] = *reinterpret_cast<const float4*>(x2 + (size_t)(j0 + jj) * D_ + 4);
    }

#pragma unroll
    for (int ii = 0; ii < TI; ++ii) {
        const int i = i0 + ii;
        // Uniform address across block -> scalar-load path, L2-resident.
        const float4 xa = *reinterpret_cast<const float4*>(x + (size_t)i * D_);
        const float4 xb = *reinterpret_cast<const float4*>(x + (size_t)i * D_ + 4);

        float r[4];
#pragma unroll
        for (int jj = 0; jj < 4; ++jj) {
            float d0 = xa.x - a[jj].x;
            float d1 = xa.y - a[jj].y;
            float d2 = xa.z - a[jj].z;
            float d3 = xa.w - a[jj].w;
            float d4 = xb.x - b[jj].x;
            float d5 = xb.y - b[jj].y;
            float d6 = xb.z - b[jj].z;
            float d7 = xb.w - b[jj].w;
            float acc;
            acc = d0 * d0 * c0;
            acc = fmaf(d1 * d1, c1, acc);
            acc = fmaf(d2 * d2, c2, acc);
            acc = fmaf(d3 * d3, c3, acc);
            acc = fmaf(d4 * d4, c4, acc);
            acc = fmaf(d5 * d5, c5, acc);
            acc = fmaf(d6 * d6, c6, acc);
            acc = fmaf(d7 * d7, c7, acc);
            r[jj] = amp2 * __expf(-acc);
        }
        // Plain write-back store: L2 absorbs bursts (fillBuffer hits ~6 TB/s
        // this way; NT write-through was the suspected limiter).
        float4 res = make_float4(r[0], r[1], r[2], r[3]);
        *reinterpret_cast<float4*>(out + (size_t)i * M_ + j0) = res;
    }
}

extern "C" void kernel_launch(void* const* d_in, const int* in_sizes, int n_in,
                              void* d_out, int out_size, void* d_ws, size_t ws_size,
                              hipStream_t stream) {
    const float* x    = (const float*)d_in[0];
    const float* x2   = (const float*)d_in[1];
    const float* ramp = (const float*)d_in[2];
    const float* rls  = (const float*)d_in[3];
    float* out = (float*)d_out;

    dim3 block(256);
    dim3 grid(M_ / 1024, N_ / TI);   // (4, 512) = 2048 blocks
    rbf_kernel<<<grid, block, 0, stream>>>(x, x2, ramp, rls, out);
}

// Round 10
// 86.945 us; speedup vs baseline: 1.5629x; 1.0271x over previous
//
#include <hip/hip_runtime.h>
#include <math.h>

#define N_ 4096
#define M_ 4096
#define D_ 8
#define TI 8                        // x-rows per block (amortizes x2 loads)
#define TINY_F 1.17549435e-38f
#define LOG2E_F 1.44269504088896f

// Numerically stable softplus: log(1+exp(v)) = max(v,0) + log1p(exp(-|v|))
__device__ __forceinline__ float softplus_stable(float v) {
    return fmaxf(v, 0.0f) + log1pf(expf(-fabsf(v)));
}

__global__ __launch_bounds__(256) void rbf_kernel(
    const float* __restrict__ x,      // (N, D)
    const float* __restrict__ x2,     // (M, D)
    const float* __restrict__ ramp,   // (1,)
    const float* __restrict__ rls,    // (D,)
    float* __restrict__ out)          // (N, M)
{
    // [0..7] = (0.5/ls^2)*log2(e)  (exp folded to exp2), [8] = amp^2
    __shared__ float s_par[D_ + 1];
    if (threadIdx.x < D_) {
        float l = softplus_stable(rls[threadIdx.x]) + TINY_F;
        s_par[threadIdx.x] = (0.5f * LOG2E_F) / (l * l);
    } else if (threadIdx.x == D_) {
        float a = softplus_stable(ramp[0]) + TINY_F;
        s_par[D_] = a * a;
    }
    __syncthreads();

    const float c0 = s_par[0], c1 = s_par[1], c2 = s_par[2], c3 = s_par[3];
    const float c4 = s_par[4], c5 = s_par[5], c6 = s_par[6], c7 = s_par[7];
    const float amp2 = s_par[D_];

    const int t  = threadIdx.x;
    const int jb = blockIdx.x * 1024;
    const int i0 = blockIdx.y * TI;

    // Lane-contiguous row ownership: thread t owns rows jb+t+{0,256,512,768}.
    // Per-lane address stride is 32 B -> coalesced loads (2 lanes/cache line),
    // vs the old 4-consecutive-rows scheme (128 B stride, 1 line per lane).
    float4 a[4], b[4];
#pragma unroll
    for (int k = 0; k < 4; ++k) {
        const size_t row = (size_t)(jb + t + k * 256) * D_;
        a[k] = *reinterpret_cast<const float4*>(x2 + row);
        b[k] = *reinterpret_cast<const float4*>(x2 + row + 4);
    }

#pragma unroll
    for (int ii = 0; ii < TI; ++ii) {
        const int i = i0 + ii;
        // Uniform address across block -> scalar-load path, L2-resident.
        const float4 xa = *reinterpret_cast<const float4*>(x + (size_t)i * D_);
        const float4 xb = *reinterpret_cast<const float4*>(x + (size_t)i * D_ + 4);

        float r[4];
#pragma unroll
        for (int k = 0; k < 4; ++k) {
            float d0 = xa.x - a[k].x;
            float d1 = xa.y - a[k].y;
            float d2 = xa.z - a[k].z;
            float d3 = xa.w - a[k].w;
            float d4 = xb.x - b[k].x;
            float d5 = xb.y - b[k].y;
            float d6 = xb.z - b[k].z;
            float d7 = xb.w - b[k].w;
            float acc;
            acc = d0 * d0 * c0;
            acc = fmaf(d1 * d1, c1, acc);
            acc = fmaf(d2 * d2, c2, acc);
            acc = fmaf(d3 * d3, c3, acc);
            acc = fmaf(d4 * d4, c4, acc);
            acc = fmaf(d5 * d5, c5, acc);
            acc = fmaf(d6 * d6, c6, acc);
            acc = fmaf(d7 * d7, c7, acc);
            // exp(-0.5 s) == exp2(-acc) with log2e pre-folded into c_d;
            // negate is a free VOP input modifier on v_exp_f32.
            r[k] = amp2 * __builtin_amdgcn_exp2f(-acc);
        }
        // 4 dword stores sharing one address register via imm offsets
        // {0,1024,2048,3072} B; each wave-store = 256 B contiguous.
        float* o = out + (size_t)i * M_ + jb + t;
        o[0]   = r[0];
        o[256] = r[1];
        o[512] = r[2];
        o[768] = r[3];
    }
}

extern "C" void kernel_launch(void* const* d_in, const int* in_sizes, int n_in,
                              void* d_out, int out_size, void* d_ws, size_t ws_size,
                              hipStream_t stream) {
    const float* x    = (const float*)d_in[0];
    const float* x2   = (const float*)d_in[1];
    const float* ramp = (const float*)d_in[2];
    const float* rls  = (const float*)d_in[3];
    float* out = (float*)d_out;

    dim3 block(256);
    dim3 grid(M_ / 1024, N_ / TI);   // (4, 512) = 2048 blocks
    rbf_kernel<<<grid, block, 0, stream>>>(x, x2, ramp, rls, out);
}

// Round 11
// 86.638 us; speedup vs baseline: 1.5685x; 1.0035x over previous
//
#include <hip/hip_runtime.h>
#include <math.h>

#define N_ 4096
#define M_ 4096
#define D_ 8
#define TI 8                        // x-rows per block
#define TINY_F 1.17549435e-38f
#define LOG2E_F 1.44269504088896f

typedef float floatx2 __attribute__((ext_vector_type(2)));  // -> v_pk_*_f32

// Numerically stable softplus: log(1+exp(v)) = max(v,0) + log1p(exp(-|v|))
__device__ __forceinline__ float softplus_stable(float v) {
    return fmaxf(v, 0.0f) + log1pf(expf(-fabsf(v)));
}

__global__ __launch_bounds__(256) void rbf_kernel(
    const float* __restrict__ x,      // (N, D)
    const float* __restrict__ x2,     // (M, D)
    const float* __restrict__ ramp,   // (1,)
    const float* __restrict__ rls,    // (D,)
    float* __restrict__ out)          // (N, M)
{
    // [0..7] = (0.5/ls^2)*log2(e)  (exp folded into exp2), [8] = amp^2
    __shared__ float s_par[D_ + 1];
    if (threadIdx.x < D_) {
        float l = softplus_stable(rls[threadIdx.x]) + TINY_F;
        s_par[threadIdx.x] = (0.5f * LOG2E_F) / (l * l);
    } else if (threadIdx.x == D_) {
        float a = softplus_stable(ramp[0]) + TINY_F;
        s_par[D_] = a * a;
    }
    __syncthreads();

    // Dim-pair packed constants (one-time).
    floatx2 cp[4];
    cp[0] = floatx2{s_par[0], s_par[1]};
    cp[1] = floatx2{s_par[2], s_par[3]};
    cp[2] = floatx2{s_par[4], s_par[5]};
    cp[3] = floatx2{s_par[6], s_par[7]};
    const float amp2 = s_par[D_];

    const int t  = threadIdx.x;
    const int jb = blockIdx.x * 1024;
    const int i0 = blockIdx.y * TI;

    // Lane-contiguous ownership: thread t owns x2 rows jb+t+{0,256,512,768}
    // (32 B lane stride -> coalesced). float4 halves ARE the dim-pairs, so
    // the floatx2 views below are register renames, not shuffles.
    floatx2 w[4][4];
#pragma unroll
    for (int k = 0; k < 4; ++k) {
        const float* r2 = x2 + (size_t)(jb + t + k * 256) * D_;
        const float4 a = *reinterpret_cast<const float4*>(r2);
        const float4 b = *reinterpret_cast<const float4*>(r2 + 4);
        w[k][0] = floatx2{a.x, a.y};
        w[k][1] = floatx2{a.z, a.w};
        w[k][2] = floatx2{b.x, b.y};
        w[k][3] = floatx2{b.z, b.w};
    }

#pragma unroll
    for (int ii = 0; ii < TI; ++ii) {
        const int i = i0 + ii;
        // Uniform address -> scalar-load path, L1/L2-hot.
        const float4 xa = *reinterpret_cast<const float4*>(x + (size_t)i * D_);
        const float4 xb = *reinterpret_cast<const float4*>(x + (size_t)i * D_ + 4);
        const floatx2 xp0 = floatx2{xa.x, xa.y};
        const floatx2 xp1 = floatx2{xa.z, xa.w};
        const floatx2 xp2 = floatx2{xb.x, xb.y};
        const floatx2 xp3 = floatx2{xb.z, xb.w};

        float r[4];
#pragma unroll
        for (int k = 0; k < 4; ++k) {
            // Packed math over dim-pairs: 12 v_pk ops per column.
            floatx2 d0 = xp0 - w[k][0];
            floatx2 acc2 = d0 * d0 * cp[0];
            floatx2 d1 = xp1 - w[k][1];
            acc2 = __builtin_elementwise_fma(d1 * d1, cp[1], acc2);
            floatx2 d2 = xp2 - w[k][2];
            acc2 = __builtin_elementwise_fma(d2 * d2, cp[2], acc2);
            floatx2 d3 = xp3 - w[k][3];
            acc2 = __builtin_elementwise_fma(d3 * d3, cp[3], acc2);
            float s = acc2.x + acc2.y;      // even+odd partial sums
            // exp(-0.5 q) == exp2(-s), log2e pre-folded; negate is free mod.
            r[k] = amp2 * __builtin_amdgcn_exp2f(-s);
        }
        // 4 dword stores off one address register (imm offsets {0,1,2,3}KB);
        // each wave-store = 256 B contiguous.
        float* o = out + (size_t)i * M_ + jb + t;
        o[0]   = r[0];
        o[256] = r[1];
        o[512] = r[2];
        o[768] = r[3];
    }
}

extern "C" void kernel_launch(void* const* d_in, const int* in_sizes, int n_in,
                              void* d_out, int out_size, void* d_ws, size_t ws_size,
                              hipStream_t stream) {
    const float* x    = (const float*)d_in[0];
    const float* x2   = (const float*)d_in[1];
    const float* ramp = (const float*)d_in[2];
    const float* rls  = (const float*)d_in[3];
    float* out = (float*)d_out;

    dim3 block(256);
    dim3 grid(M_ / 1024, N_ / TI);   // (4, 512) = 2048 blocks
    rbf_kernel<<<grid, block, 0, stream>>>(x, x2, ramp, rls, out);
}